// Round 3
// baseline (271.708 us; speedup 1.0000x reference)
//
#include <hip/hip_runtime.h>

// Problem constants
#define NB      32      // batch
#define INF     128     // in_flt
#define NPIX    64      // N
#define TSP     16      // t
#define OUTF    32      // out_flt
#define FF      16      // intermediate features
#define D_IN    768     // 3*t*t
#define D_OUT   8192    // out_flt*t*t
#define NCOL    (D_OUT*FF)   // 131072
#define OUTCH   160     // in_flt + out_flt
#define BSTRIDE 655360  // 160*64*64 floats per batch in d_out
#define MOFF    524288  // 128*64*64: offset of out_a region per batch (M scratch)

// K1: fused strided conv (128ch,4x4,stride4 -> 3ch) + x->out concat copy.
__global__ __launch_bounds__(256) void k1_conv_copy(
    const float* __restrict__ x, const float* __restrict__ wc,
    float* __restrict__ out, float* __restrict__ At)
{
    __shared__ float sW[3*128*16];     // w_conv, 24 KB
    __shared__ float sP[16][16][3];    // partials [icg][j][c3]
    const int b   = blockIdx.x >> 4;
    const int oi  = blockIdx.x & 15;
    const int tid = threadIdx.x;
    for (int idx = tid; idx < 6144; idx += 256) sW[idx] = wc[idx];
    __syncthreads();
    const int icg = tid >> 4;          // 0..15 -> ic block of 8
    const int j   = tid & 15;          // output col
    float a0 = 0.f, a1 = 0.f, a2 = 0.f;
    for (int ic8 = 0; ic8 < 8; ++ic8) {
        const int ic = icg*8 + ic8;
        #pragma unroll
        for (int ki = 0; ki < 4; ++ki) {
            const int row = 4*oi + ki;
            const float4 xv = *(const float4*)(x + ((size_t)(b*INF+ic)*NPIX + row)*NPIX + 4*j);
            *(float4*)(out + ((size_t)(b*OUTCH+ic)*NPIX + row)*NPIX + 4*j) = xv;
            const float* w0 = sW + ((0*INF+ic)*4 + ki)*4;
            const float* w1 = sW + ((1*INF+ic)*4 + ki)*4;
            const float* w2 = sW + ((2*INF+ic)*4 + ki)*4;
            a0 += xv.x*w0[0] + xv.y*w0[1] + xv.z*w0[2] + xv.w*w0[3];
            a1 += xv.x*w1[0] + xv.y*w1[1] + xv.z*w1[2] + xv.w*w1[3];
            a2 += xv.x*w2[0] + xv.y*w2[1] + xv.z*w2[2] + xv.w*w2[3];
        }
    }
    sP[icg][j][0] = a0; sP[icg][j][1] = a1; sP[icg][j][2] = a2;
    __syncthreads();
    if (tid < 48) {
        const int c3 = tid >> 4, jj = tid & 15;
        float s = 0.f;
        #pragma unroll
        for (int g = 0; g < 16; ++g) s += sP[g][jj][c3];
        const int k = c3*256 + oi*16 + jj;    // reshape(3,16,16) C-order
        At[k*32 + b] = s;
    }
}

// K2: M[b, col] = sum_k At[k][b] * T[k, col], register-tiled.
// Lane owns a 4b x 4col micro-tile (16 accs). Per k: 1 ds_read_b128 of A
// (wave-uniform addr -> free broadcast, each float reused 4x) + 1 coalesced
// global dwordx4 of T (reused 4x across the bg-waves via L1) + 16 v_fmac.
// LDS:VALU = 12:32 cyc per wave-k (R0/R1 were 96:64 -> delivery-bound).
// All of At (96 KB) staged once in LDS; block = 32 b x 256 cols, 512 thr.
__global__ __launch_bounds__(512) void k2_gemm(
    const float* __restrict__ At, const float* __restrict__ Tm,
    float* __restrict__ out)
{
    extern __shared__ float sA[];      // D_IN*32 = 24576 floats = 96 KB
    const int tid = threadIdx.x;
    {   // stage all of At, coalesced float4
        const float4* src = (const float4*)At;
        float4* dst = (float4*)sA;
        #pragma unroll
        for (int i = 0; i < 12; ++i)
            dst[tid + i*512] = src[tid + i*512];
    }
    __syncthreads();
    const int cg   = tid & 63;                 // 64 col-groups
    const int bg   = tid >> 6;                 // 8 b-groups (wave-uniform)
    const int col4 = blockIdx.x*256 + cg*4;
    float acc[4][4];
    #pragma unroll
    for (int i = 0; i < 4; ++i)
        #pragma unroll
        for (int j = 0; j < 4; ++j) acc[i][j] = 0.f;
    const float* tp = Tm + col4;
    const float* ap = sA + bg*4;
    #pragma unroll 8
    for (int k = 0; k < D_IN; ++k) {
        const float4 t4 = *(const float4*)tp;  tp += NCOL;
        const float4 a4 = *(const float4*)ap;  ap += 32;
        acc[0][0] += a4.x*t4.x; acc[0][1] += a4.x*t4.y; acc[0][2] += a4.x*t4.z; acc[0][3] += a4.x*t4.w;
        acc[1][0] += a4.y*t4.x; acc[1][1] += a4.y*t4.y; acc[1][2] += a4.y*t4.z; acc[1][3] += a4.y*t4.w;
        acc[2][0] += a4.z*t4.x; acc[2][1] += a4.z*t4.y; acc[2][2] += a4.z*t4.z; acc[2][3] += a4.z*t4.w;
        acc[3][0] += a4.w*t4.x; acc[3][1] += a4.w*t4.y; acc[3][2] += a4.w*t4.z; acc[3][3] += a4.w*t4.w;
    }
    #pragma unroll
    for (int bb = 0; bb < 4; ++bb) {
        float4 v = make_float4(acc[bb][0], acc[bb][1], acc[bb][2], acc[bb][3]);
        *(float4*)(out + (size_t)(bg*4 + bb)*BSTRIDE + MOFF + col4) = v;
    }
}

// K3: out[j,d] = sum_i exp(-sum_f |M[i,d,f]-M[j,d,f]|) - 1.
__global__ __launch_bounds__(256) void k3_pairs(
    const float* __restrict__ outM,    // d_out base (M lives in out_a slots)
    float* __restrict__ outS)
{
    extern __shared__ float sM[];      // 32*32*17 floats
    const int tid = threadIdx.x;
    const int dd0 = blockIdx.x * 32;
    for (int idx = tid; idx < 32*32*16; idx += 256) {
        const int i = idx >> 9, rem = idx & 511, d = rem >> 4, f = rem & 15;
        sM[(i*32 + d)*17 + f] =
            outM[(size_t)i*BSTRIDE + MOFF + (size_t)(dd0 + d)*16 + f];
    }
    __syncthreads();
    const int j = tid >> 3;
    for (int q = 0; q < 4; ++q) {
        const int d = (tid & 7) + q*8;
        float mj[16];
        const float* pj = sM + (j*32 + d)*17;
        #pragma unroll
        for (int f = 0; f < 16; ++f) mj[f] = pj[f];
        float acc = 0.f;
        for (int i = 0; i < 32; ++i) {
            const float* pi = sM + (i*32 + d)*17;
            float dist = 0.f;
            #pragma unroll
            for (int f = 0; f < 16; ++f) dist += fabsf(pi[f] - mj[f]);
            acc += __expf(-dist);
        }
        outS[(size_t)j*D_OUT + dd0 + d] = acc - 1.0f;
    }
}

// K4: ConvTranspose2d, stride==kernel -> no overlap.
__global__ __launch_bounds__(256) void k4_deconv(
    const float* __restrict__ outS, const float* __restrict__ wd,
    float* __restrict__ out)
{
    __shared__ float sO[32*256];       // [ic][si*16+sj]
    __shared__ float sWd[32*16];       // [ic][ki*4+kj]
    const int b   = blockIdx.x >> 5;
    const int oc  = blockIdx.x & 31;
    const int tid = threadIdx.x;
    for (int idx = tid; idx < 8192; idx += 256) sO[idx] = outS[(size_t)b*D_OUT + idx];
    for (int idx = tid; idx < 512; idx += 256) {
        const int ic = idx >> 4, r = idx & 15;
        sWd[idx] = wd[((ic*32 + oc) << 4) + r];   // IOHW: (ic, oc, ki, kj)
    }
    __syncthreads();
    float* ob = out + (size_t)b*BSTRIDE + (size_t)(128 + oc)*4096;
    for (int s = 0; s < 16; ++s) {
        const int p  = tid + (s << 8);
        const int i  = p >> 6, jc = p & 63;
        const int si = i >> 2, ki = i & 3, sj = jc >> 2, kj = jc & 3;
        float acc = 0.f;
        #pragma unroll
        for (int ic = 0; ic < 32; ++ic)
            acc += sO[ic*256 + si*16 + sj] * sWd[ic*16 + ki*4 + kj];
        ob[p] = acc;
    }
}

extern "C" void kernel_launch(void* const* d_in, const int* in_sizes, int n_in,
                              void* d_out, int out_size, void* d_ws, size_t ws_size,
                              hipStream_t stream) {
    const float* x  = (const float*)d_in[0];
    const float* wc = (const float*)d_in[1];
    const float* Tm = (const float*)d_in[2];
    const float* wd = (const float*)d_in[3];
    float* out  = (float*)d_out;
    float* At   = (float*)d_ws;                        // 98304 B
    float* outS = (float*)((char*)d_ws + (1 << 17));   // 1 MB at +128 KB

    k1_conv_copy<<<NB*TSP, 256, 0, stream>>>(x, wc, out, At);                   // 512 blocks
    k2_gemm    <<<NCOL/256, 512, D_IN*32*sizeof(float), stream>>>(At, Tm, out); // 512 blocks
    k3_pairs   <<<D_OUT/32, 256, 32*32*17*sizeof(float), stream>>>(out, outS);  // 256 blocks
    k4_deconv  <<<NB*OUTF, 256, 0, stream>>>(outS, wd, out);                    // 1024 blocks
}

// Round 4
// 222.017 us; speedup vs baseline: 1.2238x; 1.2238x over previous
//
#include <hip/hip_runtime.h>

// Problem constants
#define NB      32      // batch
#define INF     128     // in_flt
#define NPIX    64      // N
#define TSP     16      // t
#define OUTF    32      // out_flt
#define FF      16      // intermediate features
#define D_IN    768     // 3*t*t
#define D_OUT   8192    // out_flt*t*t
#define NCOL    (D_OUT*FF)   // 131072
#define OUTCH   160     // in_flt + out_flt
#define BSTRIDE 655360  // 160*64*64 floats per batch in d_out
#define MOFF    524288  // 128*64*64: offset of out_a region per batch (M scratch)

// K1: fused strided conv (128ch,4x4,stride4 -> 3ch) + x->out concat copy.
__global__ __launch_bounds__(256) void k1_conv_copy(
    const float* __restrict__ x, const float* __restrict__ wc,
    float* __restrict__ out, float* __restrict__ At)
{
    __shared__ float sW[3*128*16];     // w_conv, 24 KB
    __shared__ float sP[16][16][3];    // partials [icg][j][c3]
    const int b   = blockIdx.x >> 4;
    const int oi  = blockIdx.x & 15;
    const int tid = threadIdx.x;
    for (int idx = tid; idx < 6144; idx += 256) sW[idx] = wc[idx];
    __syncthreads();
    const int icg = tid >> 4;          // 0..15 -> ic block of 8
    const int j   = tid & 15;          // output col
    float a0 = 0.f, a1 = 0.f, a2 = 0.f;
    for (int ic8 = 0; ic8 < 8; ++ic8) {
        const int ic = icg*8 + ic8;
        #pragma unroll
        for (int ki = 0; ki < 4; ++ki) {
            const int row = 4*oi + ki;
            const float4 xv = *(const float4*)(x + ((size_t)(b*INF+ic)*NPIX + row)*NPIX + 4*j);
            *(float4*)(out + ((size_t)(b*OUTCH+ic)*NPIX + row)*NPIX + 4*j) = xv;
            const float* w0 = sW + ((0*INF+ic)*4 + ki)*4;
            const float* w1 = sW + ((1*INF+ic)*4 + ki)*4;
            const float* w2 = sW + ((2*INF+ic)*4 + ki)*4;
            a0 += xv.x*w0[0] + xv.y*w0[1] + xv.z*w0[2] + xv.w*w0[3];
            a1 += xv.x*w1[0] + xv.y*w1[1] + xv.z*w1[2] + xv.w*w1[3];
            a2 += xv.x*w2[0] + xv.y*w2[1] + xv.z*w2[2] + xv.w*w2[3];
        }
    }
    sP[icg][j][0] = a0; sP[icg][j][1] = a1; sP[icg][j][2] = a2;
    __syncthreads();
    if (tid < 48) {
        const int c3 = tid >> 4, jj = tid & 15;
        float s = 0.f;
        #pragma unroll
        for (int g = 0; g < 16; ++g) s += sP[g][jj][c3];
        const int k = c3*256 + oi*16 + jj;    // reshape(3,16,16) C-order
        At[k*32 + b] = s;
    }
}

// K2: M[b, col] = sum_k At[k][b] * T[k, col], register-tiled 4b x 4col,
// with an EXPLICIT 8-deep T-load pipeline. R3 diagnosis: VGPR_Count=32
// showed the compiler collapsed unroll-8 to ONE load in flight -> 229 us
// of pure latency. tb[8] (32 live VGPRs, static indices only) forces
// 8 loads in flight/wave = 64 KB/CU >> 9.2 KB latency-BW product.
// A reads stay on lgkmcnt (ds_read_b128 + imm offsets), separate from vmcnt.
__global__ __launch_bounds__(512) void k2_gemm(
    const float* __restrict__ At, const float* __restrict__ Tm,
    float* __restrict__ out)
{
    extern __shared__ float sA[];      // D_IN*32 = 24576 floats = 96 KB
    const int tid = threadIdx.x;
    {   // stage all of At, coalesced float4
        const float4* src = (const float4*)At;
        float4* dst = (float4*)sA;
        #pragma unroll
        for (int i = 0; i < 12; ++i)
            dst[tid + i*512] = src[tid + i*512];
    }
    __syncthreads();
    const int cg   = tid & 63;                 // 64 col-groups
    const int bg   = tid >> 6;                 // 8 b-groups (wave-uniform)
    const int col4 = blockIdx.x*256 + cg*4;
    float acc[4][4];
    #pragma unroll
    for (int i = 0; i < 4; ++i)
        #pragma unroll
        for (int j = 0; j < 4; ++j) acc[i][j] = 0.f;

    const float* tp = Tm + col4;
    const float* ap = sA + bg*4;

    float4 tb[8];                      // prefetch ring, static indices only
    #pragma unroll
    for (int i = 0; i < 8; ++i)
        tb[i] = *(const float4*)(tp + (size_t)i*NCOL);

#define K2_FMACS(t4, a4) \
    acc[0][0] += a4.x*t4.x; acc[0][1] += a4.x*t4.y; acc[0][2] += a4.x*t4.z; acc[0][3] += a4.x*t4.w; \
    acc[1][0] += a4.y*t4.x; acc[1][1] += a4.y*t4.y; acc[1][2] += a4.y*t4.z; acc[1][3] += a4.y*t4.w; \
    acc[2][0] += a4.z*t4.x; acc[2][1] += a4.z*t4.y; acc[2][2] += a4.z*t4.z; acc[2][3] += a4.z*t4.w; \
    acc[3][0] += a4.w*t4.x; acc[3][1] += a4.w*t4.y; acc[3][2] += a4.w*t4.z; acc[3][3] += a4.w*t4.w;

    for (int k0 = 0; k0 < D_IN - 8; k0 += 8) {
        #pragma unroll
        for (int i = 0; i < 8; ++i) {
            const float4 t4 = tb[i];
            tb[i] = *(const float4*)(tp + (size_t)(k0 + 8 + i)*NCOL);  // prefetch k+8
            const float4 a4 = *(const float4*)(ap + (k0 + i)*32);
            K2_FMACS(t4, a4)
        }
    }
    {   // epilogue: last 8 k, consume only
        const int k0 = D_IN - 8;
        #pragma unroll
        for (int i = 0; i < 8; ++i) {
            const float4 t4 = tb[i];
            const float4 a4 = *(const float4*)(ap + (k0 + i)*32);
            K2_FMACS(t4, a4)
        }
    }
#undef K2_FMACS

    #pragma unroll
    for (int bb = 0; bb < 4; ++bb) {
        float4 v = make_float4(acc[bb][0], acc[bb][1], acc[bb][2], acc[bb][3]);
        *(float4*)(out + (size_t)(bg*4 + bb)*BSTRIDE + MOFF + col4) = v;
    }
}

// K3: out[j,d] = sum_i exp(-sum_f |M[i,d,f]-M[j,d,f]|) - 1.
__global__ __launch_bounds__(256) void k3_pairs(
    const float* __restrict__ outM,    // d_out base (M lives in out_a slots)
    float* __restrict__ outS)
{
    extern __shared__ float sM[];      // 32*32*17 floats
    const int tid = threadIdx.x;
    const int dd0 = blockIdx.x * 32;
    for (int idx = tid; idx < 32*32*16; idx += 256) {
        const int i = idx >> 9, rem = idx & 511, d = rem >> 4, f = rem & 15;
        sM[(i*32 + d)*17 + f] =
            outM[(size_t)i*BSTRIDE + MOFF + (size_t)(dd0 + d)*16 + f];
    }
    __syncthreads();
    const int j = tid >> 3;
    for (int q = 0; q < 4; ++q) {
        const int d = (tid & 7) + q*8;
        float mj[16];
        const float* pj = sM + (j*32 + d)*17;
        #pragma unroll
        for (int f = 0; f < 16; ++f) mj[f] = pj[f];
        float acc = 0.f;
        for (int i = 0; i < 32; ++i) {
            const float* pi = sM + (i*32 + d)*17;
            float dist = 0.f;
            #pragma unroll
            for (int f = 0; f < 16; ++f) dist += fabsf(pi[f] - mj[f]);
            acc += __expf(-dist);
        }
        outS[(size_t)j*D_OUT + dd0 + d] = acc - 1.0f;
    }
}

// K4: ConvTranspose2d, stride==kernel -> no overlap.
__global__ __launch_bounds__(256) void k4_deconv(
    const float* __restrict__ outS, const float* __restrict__ wd,
    float* __restrict__ out)
{
    __shared__ float sO[32*256];       // [ic][si*16+sj]
    __shared__ float sWd[32*16];       // [ic][ki*4+kj]
    const int b   = blockIdx.x >> 5;
    const int oc  = blockIdx.x & 31;
    const int tid = threadIdx.x;
    for (int idx = tid; idx < 8192; idx += 256) sO[idx] = outS[(size_t)b*D_OUT + idx];
    for (int idx = tid; idx < 512; idx += 256) {
        const int ic = idx >> 4, r = idx & 15;
        sWd[idx] = wd[((ic*32 + oc) << 4) + r];   // IOHW: (ic, oc, ki, kj)
    }
    __syncthreads();
    float* ob = out + (size_t)b*BSTRIDE + (size_t)(128 + oc)*4096;
    for (int s = 0; s < 16; ++s) {
        const int p  = tid + (s << 8);
        const int i  = p >> 6, jc = p & 63;
        const int si = i >> 2, ki = i & 3, sj = jc >> 2, kj = jc & 3;
        float acc = 0.f;
        #pragma unroll
        for (int ic = 0; ic < 32; ++ic)
            acc += sO[ic*256 + si*16 + sj] * sWd[ic*16 + ki*4 + kj];
        ob[p] = acc;
    }
}

extern "C" void kernel_launch(void* const* d_in, const int* in_sizes, int n_in,
                              void* d_out, int out_size, void* d_ws, size_t ws_size,
                              hipStream_t stream) {
    const float* x  = (const float*)d_in[0];
    const float* wc = (const float*)d_in[1];
    const float* Tm = (const float*)d_in[2];
    const float* wd = (const float*)d_in[3];
    float* out  = (float*)d_out;
    float* At   = (float*)d_ws;                        // 98304 B
    float* outS = (float*)((char*)d_ws + (1 << 17));   // 1 MB at +128 KB

    k1_conv_copy<<<NB*TSP, 256, 0, stream>>>(x, wc, out, At);                   // 512 blocks
    k2_gemm    <<<NCOL/256, 512, D_IN*32*sizeof(float), stream>>>(At, Tm, out); // 512 blocks
    k3_pairs   <<<D_OUT/32, 256, 32*32*17*sizeof(float), stream>>>(out, outS);  // 256 blocks
    k4_deconv  <<<NB*OUTF, 256, 0, stream>>>(outS, wd, out);                    // 1024 blocks
}